// Round 3
// baseline (212.199 us; speedup 1.0000x reference)
//
#include <hip/hip_runtime.h>

typedef short bf16x8 __attribute__((ext_vector_type(8)));
typedef ushort u16x4 __attribute__((ext_vector_type(4)));
typedef float f32x4 __attribute__((ext_vector_type(4)));

__device__ __forceinline__ ushort f2b(float f) {
    uint u = __builtin_bit_cast(uint, f);
    uint r = (u + 0x7fffu + ((u >> 16) & 1u)) >> 16;
    return (ushort)r;
}
__device__ __forceinline__ float b2f(ushort s) {
    uint u = ((uint)s) << 16;
    return __builtin_bit_cast(float, u);
}

// ---------------- weight prep: f32 -> bf16, wall = [q|k|v|g] (512x128), wo ----------------
__global__ __launch_bounds__(128) void prep_kernel(
        const float* __restrict__ w_q, const float* __restrict__ w_k,
        const float* __restrict__ w_v, const float* __restrict__ w_g,
        const float* __restrict__ w_o,
        ushort* __restrict__ wall, ushort* __restrict__ wo) {
    int row = blockIdx.x, col = threadIdx.x;
    if (row < 512) {
        float val;
        if (row < 128)      val = w_q[row * 128 + col];
        else if (row < 256) val = w_k[(row - 128) * 128 + col];
        else if (row < 384) val = w_v[(row - 256) * 128 + col];
        else                val = w_g[(row - 384) * 128 + col];
        wall[row * 128 + col] = f2b(val);
    } else {
        int r = row - 512;
        wo[r * 128 + col] = f2b(w_o[r * 128 + col]);
    }
}

// ---------------- LayerNorm + pair-bias: one wave per row ----------------
// biasNT[head][k][q] (f32) so attention loads f32x4 along q.
__global__ __launch_bounds__(256) void ln_bias_kernel(
        const float* __restrict__ x, const float* __restrict__ w_ln,
        const float* __restrict__ b_ln, const float* __restrict__ w_b,
        ushort* __restrict__ h, float* __restrict__ biasNT) {
    int row = blockIdx.x * 4 + (threadIdx.x >> 6);
    int lane = threadIdx.x & 63;
    float2 v = reinterpret_cast<const float2*>(x + (size_t)row * 128)[lane];
    float s = v.x + v.y;
    float sq = v.x * v.x + v.y * v.y;
#pragma unroll
    for (int off = 32; off >= 1; off >>= 1) {
        s += __shfl_xor(s, off);
        sq += __shfl_xor(sq, off);
    }
    float mean = s * (1.0f / 128.0f);
    float var = sq * (1.0f / 128.0f) - mean * mean;
    float rstd = rsqrtf(var + 1e-5f);
    int c0 = lane * 2;
    float h0 = (v.x - mean) * rstd * w_ln[c0] + b_ln[c0];
    float h1 = (v.y - mean) * rstd * w_ln[c0 + 1] + b_ln[c0 + 1];
    ushort2 o;
    o.x = f2b(h0);
    o.y = f2b(h1);
    reinterpret_cast<ushort2*>(h + (size_t)row * 128)[lane] = o;
    // pair bias: 4 dots over this row
    float p0 = h0 * w_b[c0]       + h1 * w_b[c0 + 1];
    float p1 = h0 * w_b[128 + c0] + h1 * w_b[128 + c0 + 1];
    float p2 = h0 * w_b[256 + c0] + h1 * w_b[256 + c0 + 1];
    float p3 = h0 * w_b[384 + c0] + h1 * w_b[384 + c0 + 1];
#pragma unroll
    for (int off = 32; off >= 1; off >>= 1) {
        p0 += __shfl_xor(p0, off);
        p1 += __shfl_xor(p1, off);
        p2 += __shfl_xor(p2, off);
        p3 += __shfl_xor(p3, off);
    }
    if (lane < 4) {
        float val = (lane == 0) ? p0 : (lane == 1) ? p1 : (lane == 2) ? p2 : p3;
        // row = i*256 + j ; bias[head][j(=k)][i(=q)]
        biasNT[(size_t)lane * 65536 + (row & 255) * 256 + (row >> 8)] = val;
    }
}

// ---------------- fused projections: q,k (row-major) + vt,gT (transposed) ----------------
__global__ __launch_bounds__(256) void proj_kernel(
        const ushort* __restrict__ h, const ushort* __restrict__ wall,
        ushort* __restrict__ q, ushort* __restrict__ k,
        ushort* __restrict__ vt, ushort* __restrict__ gT) {
    __shared__ char hl[16384];     // 64 rows x 256B, XOR-swizzled
    __shared__ char tbuf[32768];   // per-wave 16 rows x 256 cols (q|k) bf16, swizzled
    int m0 = blockIdx.x * 64;
    for (int idx = threadIdx.x; idx < 1024; idx += 256) {
        int byte = idx * 16, row = byte >> 8;
        *(float4*)(hl + (byte ^ ((row & 7) << 4))) =
            ((const float4*)(h + (size_t)m0 * 128))[idx];
    }
    __syncthreads();
    int w = threadIdx.x >> 6, lane = threadIdx.x & 63;
    int lo = lane & 15, hi = lane >> 4;
    int mrow = w * 16 + lo;
    bf16x8 a[4];
#pragma unroll
    for (int ks = 0; ks < 4; ++ks) {
        int byte = mrow * 256 + ks * 64 + hi * 16;
        a[ks] = *(const bf16x8*)(hl + (byte ^ ((mrow & 7) << 4)));
    }
    char* tb = tbuf + w * 8192;
    int bb = m0 >> 8;
    int pb = (m0 & 255) + w * 16 + hi * 4;
#pragma unroll
    for (int nt = 0; nt < 32; ++nt) {
        f32x4 acc = {0.f, 0.f, 0.f, 0.f};
        const ushort* wb = wall + (size_t)(nt * 16 + lo) * 128;
#pragma unroll
        for (int ks = 0; ks < 4; ++ks) {
            bf16x8 bf = *(const bf16x8*)(wb + ks * 32 + hi * 8);
            acc = __builtin_amdgcn_mfma_f32_16x16x32_bf16(a[ks], bf, acc, 0, 0, 0);
        }
        if (nt < 16) {          // q (nt<8, pre-scaled) and k -> stage for transpose
            float sc = (nt < 8) ? 0.17677669529663687f : 1.0f;
#pragma unroll
            for (int r = 0; r < 4; ++r) {
                int row16 = hi * 4 + r;
                int byte = row16 * 512 + (nt * 16 + lo) * 2;
                *(ushort*)(tb + (byte ^ ((row16 & 7) << 4))) = f2b(acc[r] * sc);
            }
        } else if (nt < 24) {   // v -> vt[bh][d][p], direct 8B store from C-layout
            int nv = nt - 16, head = nv >> 1, d = (nv & 1) * 16 + lo;
            u16x4 t;
#pragma unroll
            for (int r = 0; r < 4; ++r) t[r] = f2b(acc[r]);
            *(u16x4*)(vt + ((size_t)(bb * 4 + head) * 32 + d) * 256 + pb) = t;
        } else {                // g -> sigmoid -> gT[c][row], direct 8B store
            int colp = (nt - 24) * 16 + lo;
            u16x4 t;
#pragma unroll
            for (int r = 0; r < 4; ++r)
                t[r] = f2b(1.0f / (1.0f + __expf(-acc[r])));
            *(u16x4*)(gT + (size_t)colp * 65536 + m0 + w * 16 + hi * 4) = t;
        }
    }
    // transposed wide stores for q,k
    int grow = m0 + w * 16 + lo;
    int p = grow & 255;
#pragma unroll
    for (int i = 0; i < 8; ++i) {
        int c = i * 4 + hi;     // 8-col chunk index, 0..31 over 256 cols
        bf16x8 val = *(const bf16x8*)(tb + ((lo * 512 + c * 16) ^ ((lo & 7) << 4)));
        if (c < 16) {
            int head = c >> 2, d0 = (c & 3) * 8;
            *(bf16x8*)(q + ((size_t)(bb * 4 + head) * 256 + p) * 32 + d0) = val;
        } else {
            int c2 = c - 16, head = c2 >> 2, d0 = (c2 & 3) * 8;
            *(bf16x8*)(k + ((size_t)(bb * 4 + head) * 256 + p) * 32 + d0) = val;
        }
    }
}

// ---------------- attention + gate + out GEMM, fused ----------------
// block = (b, qb): 64 q-rows, 4 waves = 4 heads; og tile stays in LDS.
__global__ __launch_bounds__(256) void attn_kernel(
        const ushort* __restrict__ qm, const ushort* __restrict__ km,
        const ushort* __restrict__ vtm, const ushort* __restrict__ gTm,
        const float* __restrict__ biasNT, const ushort* __restrict__ wo,
        float* __restrict__ out) {
    __shared__ char plds[4 * 8192];   // per-wave P tile 16x256 bf16, swizzled
    __shared__ char ogl[16384];       // og tile 64 x 128 bf16, swizzled
    int blk = blockIdx.x, b = blk >> 2, qb = blk & 3;
    int tid = threadIdx.x, w = tid >> 6, lane = tid & 63;
    int lo = lane & 15, hi = lane >> 4;
    int head = w;
    int bh = b * 4 + head;
    char* myp = plds + w * 8192;
    const ushort* vtb = vtm + (size_t)bh * 8192;

    for (int qs = 0; qs < 4; ++qs) {
        int qrow0 = qb * 64 + qs * 16;
        bf16x8 qa = *(const bf16x8*)(qm + ((size_t)bh * 256 + qrow0 + lo) * 32 + hi * 8);
        f32x4 s[16];
        const float* bp = biasNT + (size_t)head * 65536 + qrow0 + hi * 4;
#pragma unroll
        for (int t = 0; t < 16; ++t) {
            f32x4 c = *(const f32x4*)(bp + (size_t)(t * 16 + lo) * 256);
            bf16x8 kf = *(const bf16x8*)(km + ((size_t)bh * 256 + t * 16 + lo) * 32 + hi * 8);
            s[t] = __builtin_amdgcn_mfma_f32_16x16x32_bf16(qa, kf, c, 0, 0, 0);
        }
        float mx[4] = {-1e30f, -1e30f, -1e30f, -1e30f};
#pragma unroll
        for (int t = 0; t < 16; ++t)
#pragma unroll
            for (int r = 0; r < 4; ++r) mx[r] = fmaxf(mx[r], s[t][r]);
#pragma unroll
        for (int msk = 1; msk < 16; msk <<= 1)
#pragma unroll
            for (int r = 0; r < 4; ++r) mx[r] = fmaxf(mx[r], __shfl_xor(mx[r], msk));
        float l[4] = {0.f, 0.f, 0.f, 0.f};
#pragma unroll
        for (int t = 0; t < 16; ++t)
#pragma unroll
            for (int r = 0; r < 4; ++r) {
                float pv = __expf(s[t][r] - mx[r]);
                s[t][r] = pv;
                l[r] += pv;
            }
#pragma unroll
        for (int msk = 1; msk < 16; msk <<= 1)
#pragma unroll
            for (int r = 0; r < 4; ++r) l[r] += __shfl_xor(l[r], msk);
        float rl[4];
#pragma unroll
        for (int r = 0; r < 4; ++r) rl[r] = 1.0f / l[r];
#pragma unroll
        for (int t = 0; t < 16; ++t)
#pragma unroll
            for (int r = 0; r < 4; ++r) {
                int qr = hi * 4 + r;
                int byte = qr * 512 + (t * 16 + lo) * 2;
                *(ushort*)(myp + (byte ^ ((qr & 7) << 4))) = f2b(s[t][r]);
            }
        f32x4 a0 = {0.f, 0.f, 0.f, 0.f}, a1 = {0.f, 0.f, 0.f, 0.f};
#pragma unroll
        for (int kc = 0; kc < 8; ++kc) {
            int byte = lo * 512 + kc * 64 + hi * 16;
            bf16x8 pa = *(const bf16x8*)(myp + (byte ^ ((lo & 7) << 4)));
            bf16x8 v0 = *(const bf16x8*)(vtb + lo * 256 + kc * 32 + hi * 8);
            bf16x8 v1 = *(const bf16x8*)(vtb + (16 + lo) * 256 + kc * 32 + hi * 8);
            a0 = __builtin_amdgcn_mfma_f32_16x16x32_bf16(pa, v0, a0, 0, 0, 0);
            a1 = __builtin_amdgcn_mfma_f32_16x16x32_bf16(pa, v1, a1, 0, 0, 0);
        }
        // gate + write og tile to LDS
        int c0 = head * 32 + lo;
        u16x4 g0 = *(const u16x4*)(gTm + (size_t)c0 * 65536 + b * 256 + qrow0 + hi * 4);
        u16x4 g1 = *(const u16x4*)(gTm + (size_t)(c0 + 16) * 65536 + b * 256 + qrow0 + hi * 4);
#pragma unroll
        for (int r = 0; r < 4; ++r) {
            int rowt = qs * 16 + hi * 4 + r;
            int byte0 = rowt * 256 + c0 * 2;
            *(ushort*)(ogl + (byte0 ^ ((rowt & 7) << 4))) = f2b(a0[r] * rl[r] * b2f(g0[r]));
            int byte1 = rowt * 256 + (c0 + 16) * 2;
            *(ushort*)(ogl + (byte1 ^ ((rowt & 7) << 4))) = f2b(a1[r] * rl[r] * b2f(g1[r]));
        }
    }
    __syncthreads();
    // out GEMM: 64x128 = ogl(64x128) @ wo^T
    int mrow = w * 16 + lo;
    bf16x8 oa[4];
#pragma unroll
    for (int ks = 0; ks < 4; ++ks) {
        int byte = mrow * 256 + ks * 64 + hi * 16;
        oa[ks] = *(const bf16x8*)(ogl + (byte ^ ((mrow & 7) << 4)));
    }
    int gm0 = b * 256 + qb * 64;
#pragma unroll
    for (int nt = 0; nt < 8; ++nt) {
        f32x4 acc = {0.f, 0.f, 0.f, 0.f};
        const ushort* wb = wo + (size_t)(nt * 16 + lo) * 128;
#pragma unroll
        for (int ks = 0; ks < 4; ++ks) {
            bf16x8 bf = *(const bf16x8*)(wb + ks * 32 + hi * 8);
            acc = __builtin_amdgcn_mfma_f32_16x16x32_bf16(oa[ks], bf, acc, 0, 0, 0);
        }
#pragma unroll
        for (int r = 0; r < 4; ++r) {
            out[(size_t)(gm0 + w * 16 + hi * 4 + r) * 128 + nt * 16 + lo] = acc[r];
        }
    }
}

extern "C" void kernel_launch(void* const* d_in, const int* in_sizes, int n_in,
                              void* d_out, int out_size, void* d_ws, size_t ws_size,
                              hipStream_t stream) {
    const float* x    = (const float*)d_in[0];
    const float* w_ln = (const float*)d_in[1];
    const float* b_ln = (const float*)d_in[2];
    const float* w_b  = (const float*)d_in[3];
    const float* w_q  = (const float*)d_in[4];
    const float* w_k  = (const float*)d_in[5];
    const float* w_v  = (const float*)d_in[6];
    const float* w_g  = (const float*)d_in[7];
    const float* w_o  = (const float*)d_in[8];
    float* out = (float*)d_out;

    char* ws = (char*)d_ws;
    const size_t MB16 = (size_t)65536 * 128 * sizeof(ushort);   // 16 MB
    ushort* h      = (ushort*)(ws + 0 * MB16);
    ushort* q      = (ushort*)(ws + 1 * MB16);
    ushort* k      = (ushort*)(ws + 2 * MB16);
    ushort* vt     = (ushort*)(ws + 3 * MB16);
    ushort* gT     = (ushort*)(ws + 4 * MB16);
    float*  biasNT = (float*)(ws + 5 * MB16);                   // 1 MB
    ushort* wall   = (ushort*)(ws + 5 * MB16 + (size_t)4 * 65536 * 4);
    ushort* wo     = wall + 512 * 128;

    prep_kernel<<<640, 128, 0, stream>>>(w_q, w_k, w_v, w_g, w_o, wall, wo);
    ln_bias_kernel<<<65536 / 4, 256, 0, stream>>>(x, w_ln, b_ln, w_b, h, biasNT);
    proj_kernel<<<1024, 256, 0, stream>>>(h, wall, q, k, vt, gT);
    attn_kernel<<<1024, 256, 0, stream>>>(q, k, vt, gT, biasNT, wo, out);
}